// Round 1
// baseline (1485.104 us; speedup 1.0000x reference)
//
#include <hip/hip_runtime.h>
#include <math.h>

#define BB 4096
#define II 256
#define OO 256
#define GG 32

__device__ __forceinline__ float softplus(float x) {
    // log1p(exp(x)) stable form
    return fmaxf(x, 0.f) + log1pf(expf(-fabsf(x)));
}

// ---------------------------------------------------------------------------
// Precompute combined coefficients into workspace:
//   wmu[g,o,i]  = gw_mu[o,i] + sp(gw_rho[o,i]) * rw_mu[g,o,i]
//   wsig[g,o,i] = sp(gw_rho[o,i]) * sp(rw_rho[g,o,i])
//   bmu[g,o]    = gb_mu[o] + sp(gb_rho[o]) * rb_mu[g,o]
//   bsig[g,o]   = sp(gb_rho[o]) * sp(rb_rho[g,o])
//   ard[i]      = sp(alpha[i]) * sp(beta[i])
// ---------------------------------------------------------------------------
__global__ __launch_bounds__(256) void precompute_kernel(
    const float* __restrict__ gw_mu, const float* __restrict__ gw_rho,
    const float* __restrict__ gb_mu, const float* __restrict__ gb_rho,
    const float* __restrict__ rw_mu, const float* __restrict__ rw_rho,
    const float* __restrict__ rb_mu, const float* __restrict__ rb_rho,
    const float* __restrict__ alpha, const float* __restrict__ beta,
    float* __restrict__ wmu, float* __restrict__ wsig,
    float* __restrict__ bmu, float* __restrict__ bsig,
    float* __restrict__ ard)
{
    const int tid = blockIdx.x * blockDim.x + threadIdx.x;
    const int stride = gridDim.x * blockDim.x;
    const int N = GG * OO * II;
    for (int t = tid; t < N; t += stride) {
        int oi = t & (OO * II - 1);
        float sg = softplus(gw_rho[oi]);
        wmu[t]  = gw_mu[oi] + sg * rw_mu[t];
        wsig[t] = sg * softplus(rw_rho[t]);
    }
    for (int t = tid; t < GG * OO; t += stride) {
        int o = t & (OO - 1);
        float sb = softplus(gb_rho[o]);
        bmu[t]  = gb_mu[o] + sb * rb_mu[t];
        bsig[t] = sb * softplus(rb_rho[t]);
    }
    for (int t = tid; t < II; t += stride) {
        ard[t] = softplus(alpha[t]) * softplus(beta[t]);
    }
}

// ---------------------------------------------------------------------------
// KL reduction. Grid-stride over the big (G,O,I) term; small terms folded in.
// Block partial sums -> one atomicAdd per block.
// ---------------------------------------------------------------------------
__global__ __launch_bounds__(256) void kl_kernel(
    const float* __restrict__ gw_mu, const float* __restrict__ gw_rho,
    const float* __restrict__ gb_rho,
    const float* __restrict__ rw_mu, const float* __restrict__ rw_rho,
    const float* __restrict__ alpha, const float* __restrict__ beta,
    float* __restrict__ kl_out)
{
    const float NHL2PI = -0.918938533204672742f; // -0.5*log(2*pi)
    const int tid = blockIdx.x * blockDim.x + threadIdx.x;
    const int stride = gridDim.x * blockDim.x;
    float acc = 0.f;

    // indiv_kl over (G,O,I)
    const int N = GG * OO * II;
    for (int t = tid; t < N; t += stride) {
        float sr = softplus(rw_rho[t]);
        float mu = rw_mu[t];
        acc += NHL2PI - logf(sr) + 0.5f * (sr * sr + mu * mu) - 0.5f;
    }
    // group_kl + half_normal(gw_sigma) over (O,I)
    for (int t = tid; t < OO * II; t += stride) {
        float sg = softplus(gw_rho[t]);
        float L  = logf(sg);
        float mu = gw_mu[t];
        acc += -2.f * L + sg * sg + 0.5f * (mu * mu + L * L) - 1.f + NHL2PI;
    }
    // half_normal(gb_sigma) over (O,)
    for (int t = tid; t < OO; t += stride) {
        float sb = softplus(gb_rho[t]);
        float L  = logf(sb);
        acc += NHL2PI - L + 0.5f * (L * L + sb * sb) - 0.5f;
    }
    // ard terms over (I,)
    for (int t = tid; t < II; t += stride) {
        acc += softplus(alpha[t]) + softplus(beta[t]);
    }

    // wave reduce (64 lanes)
    for (int off = 32; off; off >>= 1) acc += __shfl_down(acc, off);
    __shared__ float red[4];
    int lane = threadIdx.x & 63, w = threadIdx.x >> 6;
    if (lane == 0) red[w] = acc;
    __syncthreads();
    if (threadIdx.x == 0) {
        atomicAdd(kl_out, red[0] + red[1] + red[2] + red[3]);
    }
}

// ---------------------------------------------------------------------------
// Main kernel: one wave per (b,o) row. Lane l handles i = 4*l..4*l+3 (float4).
//   out[b,o] = sum_i x[b,i]*ard[i]*(wmu[g,o,i] + wsig[g,o,i]*eps_w[b,o,i])
//            + bmu[g,o] + bsig[g,o]*eps_b[b,o]
// eps_w row load: 64 lanes x 16B = 1 KiB fully coalesced.
// ---------------------------------------------------------------------------
__global__ __launch_bounds__(256) void main_kernel(
    const float* __restrict__ x,
    const float* __restrict__ eps_w, const float* __restrict__ eps_b,
    const int* __restrict__ gid,
    const float* __restrict__ wmu, const float* __restrict__ wsig,
    const float* __restrict__ bmu, const float* __restrict__ bsig,
    const float* __restrict__ ard,
    float* __restrict__ out)
{
    const int wave = (blockIdx.x * 256 + threadIdx.x) >> 6; // global wave id
    const int lane = threadIdx.x & 63;
    const int b = wave >> 8;    // / OO
    const int o = wave & 255;   // % OO
    const int g = gid[b];
    const int i0 = lane * 4;

    const float4 e  = *(const float4*)(eps_w + ((size_t)b * OO + o) * II + i0);
    const float4 wm = *(const float4*)(wmu + ((size_t)g * OO + o) * II + i0);
    const float4 wv = *(const float4*)(wsig + ((size_t)g * OO + o) * II + i0);
    const float4 xv = *(const float4*)(x + (size_t)b * II + i0);
    const float4 av = *(const float4*)(ard + i0);

    float s = xv.x * av.x * (wm.x + wv.x * e.x)
            + xv.y * av.y * (wm.y + wv.y * e.y)
            + xv.z * av.z * (wm.z + wv.z * e.z)
            + xv.w * av.w * (wm.w + wv.w * e.w);

    for (int off = 32; off; off >>= 1) s += __shfl_down(s, off);

    if (lane == 0) {
        float bias = bmu[g * OO + o] + bsig[g * OO + o] * eps_b[(size_t)b * OO + o];
        out[(size_t)b * OO + o] = s + bias;
    }
}

// ---------------------------------------------------------------------------
// Fallback main kernel if workspace is too small: compute softplus inline.
// Slow but correct; only taken if ws_size < required bytes.
// ---------------------------------------------------------------------------
__global__ __launch_bounds__(256) void main_kernel_inline(
    const float* __restrict__ x,
    const float* __restrict__ gw_mu, const float* __restrict__ gw_rho,
    const float* __restrict__ gb_mu, const float* __restrict__ gb_rho,
    const float* __restrict__ rw_mu, const float* __restrict__ rw_rho,
    const float* __restrict__ rb_mu, const float* __restrict__ rb_rho,
    const float* __restrict__ alpha, const float* __restrict__ beta,
    const float* __restrict__ eps_w, const float* __restrict__ eps_b,
    const int* __restrict__ gid,
    float* __restrict__ out)
{
    const int wave = (blockIdx.x * 256 + threadIdx.x) >> 6;
    const int lane = threadIdx.x & 63;
    const int b = wave >> 8;
    const int o = wave & 255;
    const int g = gid[b];
    const int i0 = lane * 4;

    float s = 0.f;
    for (int k = 0; k < 4; ++k) {
        int i = i0 + k;
        size_t oi = (size_t)o * II + i;
        size_t goi = ((size_t)g * OO + o) * II + i;
        float sg = softplus(gw_rho[oi]);
        float wm = gw_mu[oi] + sg * rw_mu[goi];
        float wv = sg * softplus(rw_rho[goi]);
        float ep = eps_w[((size_t)b * OO + o) * II + i];
        float ar = softplus(alpha[i]) * softplus(beta[i]);
        s += x[(size_t)b * II + i] * ar * (wm + wv * ep);
    }
    for (int off = 32; off; off >>= 1) s += __shfl_down(s, off);
    if (lane == 0) {
        float sb = softplus(gb_rho[o]);
        float bias = gb_mu[o] + sb * (rb_mu[g * OO + o] + softplus(rb_rho[g * OO + o]) * eps_b[(size_t)b * OO + o]);
        out[(size_t)b * OO + o] = s + bias;
    }
}

extern "C" void kernel_launch(void* const* d_in, const int* in_sizes, int n_in,
                              void* d_out, int out_size, void* d_ws, size_t ws_size,
                              hipStream_t stream)
{
    const float* x      = (const float*)d_in[0];
    const float* gw_mu  = (const float*)d_in[1];
    const float* gw_rho = (const float*)d_in[2];
    const float* gb_mu  = (const float*)d_in[3];
    const float* gb_rho = (const float*)d_in[4];
    const float* rw_mu  = (const float*)d_in[5];
    const float* rw_rho = (const float*)d_in[6];
    const float* rb_mu  = (const float*)d_in[7];
    const float* rb_rho = (const float*)d_in[8];
    const float* alpha  = (const float*)d_in[9];
    const float* beta   = (const float*)d_in[10];
    const float* eps_w  = (const float*)d_in[11];
    const float* eps_b  = (const float*)d_in[12];
    const int*   gid    = (const int*)d_in[13];

    float* out = (float*)d_out;
    float* kl  = out + (size_t)BB * OO;   // scalar KL output slot

    // zero the KL accumulator (d_out is poisoned before every launch)
    hipMemsetAsync(kl, 0, sizeof(float), stream);

    // KL reduction (independent of workspace)
    kl_kernel<<<1024, 256, 0, stream>>>(gw_mu, gw_rho, gb_rho, rw_mu, rw_rho,
                                        alpha, beta, kl);

    const size_t n_wmu  = (size_t)GG * OO * II;
    const size_t needed = (2 * n_wmu + 2 * (size_t)GG * OO + II) * sizeof(float);
    const int n_blocks_main = (BB * OO) / 4; // 4 waves per 256-thread block

    if (ws_size >= needed) {
        float* wmu  = (float*)d_ws;
        float* wsig = wmu + n_wmu;
        float* bmu  = wsig + n_wmu;
        float* bsig = bmu + (size_t)GG * OO;
        float* ard  = bsig + (size_t)GG * OO;

        precompute_kernel<<<2048, 256, 0, stream>>>(
            gw_mu, gw_rho, gb_mu, gb_rho, rw_mu, rw_rho, rb_mu, rb_rho,
            alpha, beta, wmu, wsig, bmu, bsig, ard);

        main_kernel<<<n_blocks_main, 256, 0, stream>>>(
            x, eps_w, eps_b, gid, wmu, wsig, bmu, bsig, ard, out);
    } else {
        main_kernel_inline<<<n_blocks_main, 256, 0, stream>>>(
            x, gw_mu, gw_rho, gb_mu, gb_rho, rw_mu, rw_rho, rb_mu, rb_rho,
            alpha, beta, eps_w, eps_b, gid, out);
    }
}